// Round 16
// baseline (224.654 us; speedup 1.0000x reference)
//
#include <hip/hip_runtime.h>

#define Bn 4
#define Cn 256
#define C8 32
#define Hn 64
#define Wn 64
#define HWn 4096
#define PADR 80
#define ROWS (HWn + 2 * PADR)   // 4256 padded pixel-rows per batch
#define MARGIN 6e-3f

typedef __bf16 bf16x8 __attribute__((ext_vector_type(8)));
typedef float floatx4 __attribute__((ext_vector_type(4)));
typedef unsigned short u16x8 __attribute__((ext_vector_type(8)));

__device__ __forceinline__ unsigned short f2bf(float f) {
  union { float f; unsigned int u; } c; c.f = f;
  unsigned int u = c.u;
  return (unsigned short)((u + 0x7FFFu + ((u >> 16) & 1u)) >> 16);  // RNE
}
__device__ __forceinline__ float bf2f(unsigned short h) {
  union { unsigned int u; float f; } c; c.u = ((unsigned int)h) << 16;
  return c.f;
}
__device__ __forceinline__ void gl_lds16(const void* g, void* l) {
  __builtin_amdgcn_global_load_lds(
      (__attribute__((address_space(1))) void*)(uintptr_t)g,
      (__attribute__((address_space(3))) void*)(uintptr_t)l, 16, 0, 0);
}

// ---------------------------------------------------------------------------
// L1 (R20): proj / cat / prep co-launched, SEQUENTIAL block ordering:
// bx<512 proj, 512<=bx<1024 cat, bx>=1024 prep. Prep: tap-fused Wfb
// transpose (9 consecutive floats in, 9 coalesced bf16 streams out).
// ---------------------------------------------------------------------------
__global__ __launch_bounds__(1024) void proj_cat_prep(
    const float* __restrict__ cross_x, const float* __restrict__ front_x,
    const float* __restrict__ front_hat,
    const float* __restrict__ Wq, const float* __restrict__ bq,
    const float* __restrict__ Wk, const float* __restrict__ bk,
    const float* __restrict__ Wv, const float* __restrict__ Wf,
    float* __restrict__ qf, float* __restrict__ kf,
    unsigned short* __restrict__ qhi, unsigned short* __restrict__ qlo,
    unsigned short* __restrict__ khi, unsigned short* __restrict__ klo,
    unsigned short* __restrict__ Wvb, unsigned short* __restrict__ Wfb,
    unsigned short* __restrict__ catF, unsigned short* __restrict__ xht,
    unsigned short* __restrict__ zpad, int* __restrict__ cnt) {
  union SMu {
    struct { float Wl[8192]; float part[3 * 4 * 8 * 64]; } pj;   // 56KB
    unsigned short tile[4][64][66];                               // 33.8KB
  };
  __shared__ __align__(16) SMu sm;

  int bx = blockIdx.x;
  int tid1k = threadIdx.x;

  if (bx >= 1024) {
    // ================= prep path: 160 blocks x 1024 threads ================
    size_t t = (size_t)(bx - 1024) * 1024 + tid1k;
    if (t == 0) cnt[0] = 0;
    if (t < 256) zpad[t] = 0;
    if (t < 131072) {
      const float* src = Wf + t * 9;
#pragma unroll
      for (int k = 0; k < 9; ++k)
        Wfb[(size_t)k * 131072 + t] = f2bf(src[k]);
    }
    if (t < 163840) {           // catF pad rows (2*PADR rows x 256 ch x 4 b)
      int col = (int)(t & 255);
      int r4 = (int)(t >> 8);
      int bb = r4 / 160, rr = r4 % 160;
      int row = (rr < PADR) ? rr : (HWn + rr);
      catF[((size_t)bb * ROWS + row) * 256 + col] = 0;
    }
    if (t < 65536) Wvb[t] = f2bf(Wv[t]);   // [o][c] row-major already
    return;
  }

  if (bx >= 512) {
    // ================= cat path: id 0..511 =================
    int id = bx - 512;
    int j0 = (id & 63) * 64;
    int bz = id >> 6;                  // 0..7
    int b = bz >> 1, which = bz & 1;
    int g4 = tid1k >> 8;               // 4 groups of 256 threads
    int tid = tid1k & 255;
    int ci0 = g4 * 64;

    const float* src = (which == 0) ? front_x : front_hat;
#pragma unroll
    for (int u = tid; u < 1024; u += 256) {
      int cl = u >> 4, h4 = (u & 15) * 4;
      floatx4 v = *reinterpret_cast<const floatx4*>(
          &src[((size_t)(b * Cn + ci0 + cl)) * HWn + j0 + h4]);
#pragma unroll
      for (int k = 0; k < 4; ++k) sm.tile[g4][cl][h4 + k] = f2bf(v[k]);
    }
    __syncthreads();
#pragma unroll
    for (int u = tid; u < 512; u += 256) {
      int oct = u & 7, hw_l = u >> 3;
      u16x8 val;
#pragma unroll
      for (int k = 0; k < 8; ++k) val[k] = sm.tile[g4][oct * 8 + k][hw_l];
      if (which == 0)
        *reinterpret_cast<u16x8*>(
            &catF[((size_t)b * ROWS + PADR + j0 + hw_l) * 256 + ci0 + oct * 8]) = val;
      else
        *reinterpret_cast<u16x8*>(
            &xht[((size_t)b * HWn + j0 + hw_l) * 256 + ci0 + oct * 8]) = val;
    }
    return;
  }

  // ================= proj path: id 0..511 =================
  int id = bx;
  int tid = tid1k;
  int lane = tid & 63, wv = tid >> 6;    // 16 waves
  int slice = wv & 3;                    // o-slice (8 o each)
  int chunk = wv >> 2;                   // c-chunk (64 c each)
  int jb = id & 63;
  int b = (id >> 6) & 3;
  int z = id >> 8;
  int j = jb * 64 + lane;
  const float* x = (z == 0) ? cross_x : front_x;
  const float* Wraw = (z == 0) ? Wq : Wk;
  const float* bd = (z == 0) ? bq : bk;
  float* outp = (z == 0) ? qf : kf;
  unsigned short* hip_ = (z == 0) ? qhi : khi;
  unsigned short* lop_ = (z == 0) ? qlo : klo;
  int o0 = slice * 8;
  int c0 = chunk * 64;

  float* Wl = sm.pj.Wl;
  float* part = sm.pj.part;

  for (int u = tid; u < 8192; u += 1024) {
    int c = u >> 5, o = u & 31;
    Wl[u] = Wraw[o * 256 + c];                    // transpose on load (L2-hot)
  }
  __syncthreads();

  const float* xb = x + (size_t)b * Cn * HWn + j;
  floatx4 a0 = (floatx4)0.0f, a1 = (floatx4)0.0f;
#pragma unroll 16
  for (int c = c0; c < c0 + 64; ++c) {
    float xv = xb[(size_t)c * HWn];
    floatx4 wa = *reinterpret_cast<const floatx4*>(&Wl[c * 32 + o0]);      // broadcast
    floatx4 wb = *reinterpret_cast<const floatx4*>(&Wl[c * 32 + o0 + 4]);
    a0 += wa * xv;
    a1 += wb * xv;
  }
  if (chunk > 0) {
    float* dst = &part[(((chunk - 1) * 4 + slice) * 8) * 64];
#pragma unroll
    for (int o = 0; o < 4; ++o) { dst[o * 64 + lane] = a0[o]; dst[(o + 4) * 64 + lane] = a1[o]; }
  }
  __syncthreads();
  if (chunk != 0) return;
#pragma unroll
  for (int q = 0; q < 3; ++q) {
    const float* src = &part[((q * 4 + slice) * 8) * 64];
#pragma unroll
    for (int o = 0; o < 4; ++o) { a0[o] += src[o * 64 + lane]; a1[o] += src[(o + 4) * 64 + lane]; }
  }
  float acc[8];
#pragma unroll
  for (int o = 0; o < 4; ++o) { acc[o] = a0[o] + bd[o0 + o]; acc[o + 4] = a1[o] + bd[o0 + 4 + o]; }

  float* op = outp + ((size_t)b * HWn + j) * C8 + o0;
  u16x8 hv, lv;
#pragma unroll
  for (int o = 0; o < 8; ++o) {
    op[o] = acc[o];
    unsigned short h = f2bf(acc[o]);
    hv[o] = h;
    lv[o] = f2bf(acc[o] - bf2f(h));
  }
  *reinterpret_cast<u16x8*>(hip_ + ((size_t)b * HWn + j) * C8 + o0) = hv;
  *reinterpret_cast<u16x8*>(lop_ + ((size_t)b * HWn + j) * C8 + o0) = lv;
}

// ---------------------------------------------------------------------------
// L2 (R25): energy, 64-query tile + branchless med3 inner loop + explicit
// distance-1 REGISTER PREFETCH of the K tiles: next iteration's kh/kl loads
// are issued BEFORE the current compute block, so ~130cy of med3/MFMA work
// covers the ~200-300cy L2 load latency (energy is latency-bound: R23 ruled
// out L2-BW and occupancy). Arithmetic order identical -> bit-identical.
// ---------------------------------------------------------------------------
__global__ __launch_bounds__(1024) void energy_approx(
    const unsigned short* __restrict__ khi, const unsigned short* __restrict__ klo,
    const unsigned short* __restrict__ qhi, const unsigned short* __restrict__ qlo,
    float* __restrict__ star, int* __restrict__ argb,
    int* __restrict__ cnt, int* __restrict__ list) {
  int b = blockIdx.y;
  int j0 = blockIdx.x * 64;
  int tid = threadIdx.x;
  int lane = tid & 63, wv = tid >> 6;   // wv 0..15
  int lm = lane & 15, lq = lane >> 4;

  __shared__ float bv1S[16][64];
  __shared__ int   bi1S[16][64];
  __shared__ float bv2S[16][64];

  bf16x8 qh[4], ql[4];
#pragma unroll
  for (int s = 0; s < 4; ++s) {
    int j = j0 + s * 16 + lm;
    qh[s] = *reinterpret_cast<const bf16x8*>(qhi + ((size_t)b * HWn + j) * 32 + lq * 8);
    ql[s] = *reinterpret_cast<const bf16x8*>(qlo + ((size_t)b * HWn + j) * 32 + lq * 8);
  }
  const unsigned short* kh_base = khi + (size_t)b * HWn * 32 + lq * 8;
  const unsigned short* kl_base = klo + (size_t)b * HWn * 32 + lq * 8;

  float b1[4], b2[4];
#pragma unroll
  for (int s = 0; s < 4; ++s) { b1[s] = -3.0e38f; b2[s] = -3.0e38f; }

  int ibase = wv * 256;
  // prefetch pipeline: tile for it=0
  bf16x8 ah = *reinterpret_cast<const bf16x8*>(kh_base + (size_t)(ibase + lm) * 32);
  bf16x8 al = *reinterpret_cast<const bf16x8*>(kl_base + (size_t)(ibase + lm) * 32);
#pragma unroll 2
  for (int it = 0; it < 16; ++it) {
    bf16x8 ahn, aln;
    if (it < 15) {
      int i0n = ibase + (it + 1) * 16;
      ahn = *reinterpret_cast<const bf16x8*>(kh_base + (size_t)(i0n + lm) * 32);
      aln = *reinterpret_cast<const bf16x8*>(kl_base + (size_t)(i0n + lm) * 32);
    }
#pragma unroll
    for (int s = 0; s < 4; ++s) {
      floatx4 acc = (floatx4)0.0f;
      acc = __builtin_amdgcn_mfma_f32_16x16x32_bf16(ah, qh[s], acc, 0, 0, 0);
      acc = __builtin_amdgcn_mfma_f32_16x16x32_bf16(ah, ql[s], acc, 0, 0, 0);
      acc = __builtin_amdgcn_mfma_f32_16x16x32_bf16(al, qh[s], acc, 0, 0, 0);
#pragma unroll
      for (int r = 0; r < 4; ++r) {
        unsigned code = (unsigned)(it * 4 + r);   // SGPR-uniform per (it,r)
        union { float f; unsigned u; } cv; cv.f = acc[r];
        cv.u = (cv.u & ~63u) | code;              // v_and_or_b32
        float vp = cv.f;
        // exact new second-best: median(vp, b1_old, b2_old)
        b2[s] = __builtin_amdgcn_fmed3f(vp, b1[s], b2[s]);
        b1[s] = fmaxf(b1[s], vp);
      }
    }
    ah = ahn; al = aln;
  }
  int i1[4];
#pragma unroll
  for (int s = 0; s < 4; ++s) {
    union { float f; unsigned u; } cv; cv.f = b1[s];
    unsigned code = cv.u & 63u;                   // (it<<2)|r of the winner
    i1[s] = ibase + (int)(code >> 2) * 16 + lq * 4 + (int)(code & 3u);
  }
#pragma unroll
  for (int s = 0; s < 4; ++s) {
#pragma unroll
    for (int m = 16; m <= 32; m <<= 1) {
      float ob1 = __shfl_xor(b1[s], m, 64);
      int oi1 = __shfl_xor(i1[s], m, 64);
      float ob2 = __shfl_xor(b2[s], m, 64);
      float c2;
      if (ob1 > b1[s] || (ob1 == b1[s] && oi1 < i1[s])) {
        c2 = fmaxf(b1[s], ob2);
        b1[s] = ob1; i1[s] = oi1;
      } else {
        c2 = fmaxf(ob1, b2[s]);
      }
      b2[s] = c2;
    }
    if (lq == 0) {
      bv1S[wv][s * 16 + lm] = b1[s];
      bi1S[wv][s * 16 + lm] = i1[s];
      bv2S[wv][s * 16 + lm] = b2[s];
    }
  }
  __syncthreads();
  if (tid < 64) {
    float B1 = bv1S[0][tid];
    int I1 = bi1S[0][tid];
    float B2 = bv2S[0][tid];
#pragma unroll
    for (int w = 1; w < 16; ++w) {
      float v1 = bv1S[w][tid];
      int ii = bi1S[w][tid];
      float v2 = bv2S[w][tid];
      if (v1 > B1) { B2 = fmaxf(B1, v2); B1 = v1; I1 = ii; }
      else B2 = fmaxf(B2, v1);
    }
    size_t o = (size_t)b * HWn + j0 + tid;
    union { float f; unsigned u; } cs; cs.f = B1;
    cs.u &= ~63u;                                 // strip packed index bits
    star[o] = cs.f;
    argb[o] = I1;
    if (B1 - B2 < MARGIN) {
      int slot = atomicAdd(cnt, 1);
      list[slot] = (b << 12) | (j0 + (int)tid);
    }
  }
}

// ---------------------------------------------------------------------------
// L3 (R25): recheck + proj_v co-launch, SEQUENTIAL block ordering (R20
// pattern): projv blocks [0,256) dispatch first and pack CUs uniformly;
// recheck [256,512) fills the drain. Bodies unchanged.
// ---------------------------------------------------------------------------
__global__ __launch_bounds__(256) void recheck_projv(
    const unsigned short* __restrict__ xht, const unsigned short* __restrict__ Wvb,
    const float* __restrict__ bv, unsigned short* __restrict__ vbf,
    const float* __restrict__ qf, const float* __restrict__ kf,
    const int* __restrict__ cnt, const int* __restrict__ list,
    float* __restrict__ star, int* __restrict__ argb) {
  int bx = blockIdx.x;
  if (bx < 256) {
    // ================= proj_v path: id 0..255 =================
    int id = bx;
    int m0 = (id & 31) * 128;
    int o0 = ((id >> 5) & 1) * 128;
    int b = id >> 6;
    int tid = threadIdx.x;
    int lane = tid & 63, wv = tid >> 6;
    int wm = wv >> 1, wn = wv & 1;
    int lm = lane & 15, lq = lane >> 4;

    union SMu {
      struct { unsigned short A[2][128 * 32]; unsigned short B[2][128 * 32]; } st;
      unsigned short TS[128 * 136];
    };
    __shared__ __align__(16) SMu sm;

    floatx4 acc[4][4];
#pragma unroll
    for (int im = 0; im < 4; ++im)
#pragma unroll
      for (int in = 0; in < 4; ++in) acc[im][in] = (floatx4)0.0f;

    const int srow = lane >> 2;
    const int soff = (((lane & 3) ^ ((lane >> 3) & 3)) * 8);   // swizzled source chunk
    const int sa = (lq ^ ((lm >> 1) & 3)) * 8;                 // swizzled read column
    const unsigned short* ag = Wvb + (size_t)o0 * 256;
    const unsigned short* bg = xht + ((size_t)b * HWn + m0) * 256;

    auto STAGE = [&](int buf, int kc) {
#pragma unroll
      for (int i = 0; i < 2; ++i) {
        int r0 = wv * 32 + i * 16;
        gl_lds16(ag + ((size_t)(r0 + srow)) * 256 + kc + soff, &sm.st.A[buf][r0 * 32]);
        gl_lds16(bg + ((size_t)(r0 + srow)) * 256 + kc + soff, &sm.st.B[buf][r0 * 32]);
      }
    };
    auto COMPUTE = [&](int buf) {
      bf16x8 afr[4];
#pragma unroll
      for (int im = 0; im < 4; ++im)
        afr[im] = *reinterpret_cast<const bf16x8*>(
            &sm.st.A[buf][(wm * 64 + im * 16 + lm) * 32 + sa]);
#pragma unroll
      for (int in = 0; in < 4; ++in) {
        bf16x8 bfr = *reinterpret_cast<const bf16x8*>(
            &sm.st.B[buf][(wn * 64 + in * 16 + lm) * 32 + sa]);
#pragma unroll
        for (int im = 0; im < 4; ++im)
          acc[im][in] = __builtin_amdgcn_mfma_f32_16x16x32_bf16(
              afr[im], bfr, acc[im][in], 0, 0, 0);
      }
    };

    STAGE(0, 0);
#pragma unroll 2
    for (int st = 0; st < 8; ++st) {
      __builtin_amdgcn_s_barrier();            // buf[(st+1)&1] free to overwrite
      if (st < 7) {
        STAGE((st + 1) & 1, (st + 1) * 32);
        asm volatile("s_waitcnt vmcnt(4)" ::: "memory");   // tile st landed
      } else {
        asm volatile("s_waitcnt vmcnt(0)" ::: "memory");
      }
      __builtin_amdgcn_s_barrier();
      __builtin_amdgcn_sched_barrier(0);
      COMPUTE(st & 1);
    }
    __builtin_amdgcn_s_barrier();   // all waves done reading before TS overwrite

    // epilogue: TS aliases the (now dead) stage buffers.
#pragma unroll
    for (int in = 0; in < 4; ++in) {
      int pl = wn * 64 + in * 16 + lm;
#pragma unroll
      for (int im = 0; im < 4; ++im) {
#pragma unroll
        for (int r = 0; r < 4; ++r) {
          int ol = wm * 64 + im * 16 + lq * 4 + r;
          sm.TS[pl * 136 + ol] = f2bf(acc[im][in][r] + bv[o0 + ol]);
        }
      }
    }
    __syncthreads();
    for (int idx = tid; idx < 128 * 16; idx += 256) {
      int p = idx >> 4, ch = idx & 15;
      u16x8 val = *reinterpret_cast<const u16x8*>(&sm.TS[p * 136 + ch * 8]);
      *reinterpret_cast<u16x8*>(
          &vbf[((size_t)b * HWn + m0 + p) * 256 + o0 + ch * 8]) = val;
    }
  } else {
    // ================= recheck path: stride 256 over list =================
    __shared__ double bvS[4];
    __shared__ int biS[4];
    int n = cnt[0];
    int tid = threadIdx.x;
    int lane = tid & 63, wv = tid >> 6;
    for (int idx = bx - 256; idx < n; idx += 256) {
      int e = list[idx];
      int b = e >> 12, j = e & 4095;
      const float* qp = qf + ((size_t)b * HWn + j) * 32;
      double qj[32];
#pragma unroll
      for (int o = 0; o < 32; ++o) qj[o] = (double)qp[o];
      double best = -1.0e300;
      int bi = 1 << 30;
      for (int i = tid; i < HWn; i += 256) {
        const float* kp = kf + ((size_t)b * HWn + i) * 32;
        double s = 0.0;
#pragma unroll
        for (int o = 0; o < 32; ++o) s += (double)kp[o] * qj[o];
        if (s > best) { best = s; bi = i; }
      }
#pragma unroll
      for (int m = 1; m < 64; m <<= 1) {
        double ob = __shfl_xor(best, m, 64);
        int oi = __shfl_xor(bi, m, 64);
        if (ob > best || (ob == best && oi < bi)) { best = ob; bi = oi; }
      }
      if (lane == 0) { bvS[wv] = best; biS[wv] = bi; }
      __syncthreads();
      if (tid == 0) {
#pragma unroll
        for (int w = 1; w < 4; ++w) {
          if (bvS[w] > best || (bvS[w] == best && biS[w] < bi)) {
            best = bvS[w]; bi = biS[w];
          }
        }
        star[(size_t)b * HWn + j] = (float)best;
        argb[(size_t)b * HWn + j] = bi;
      }
      __syncthreads();
    }
  }
}

// ---------------------------------------------------------------------------
// L4 (R24): conv3x3 implicit GEMM, single-buffer serial staging + flat
// T-gather, 4 blocks/CU (zero tail). Proven ~45 us.
// ---------------------------------------------------------------------------
__global__ __launch_bounds__(256) void conv_mfma(
    const unsigned short* __restrict__ catF, const unsigned short* __restrict__ Wfb,
    const unsigned short* __restrict__ vbf, const int* __restrict__ argb,
    const unsigned short* __restrict__ zpad, unsigned short* __restrict__ Pg) {
  int m0 = blockIdx.x * 128;
  int o0 = blockIdx.y * 128;
  int bz = blockIdx.z;
  int b = bz / 3, g = bz % 3;      // g = dy+1
  int dy = g - 1;
  int tid = threadIdx.x;
  int lane = tid & 63;
  int wv = tid >> 6;
  int wm = wv >> 1, wn = wv & 1;
  int lm = lane & 15, lq = lane >> 4;
  const bool lane_first = (lm == 0);
  const bool lane_last = (lm == 15);

  __shared__ __align__(16) unsigned short AS[3 * 128 * 32];  // 24KB
  __shared__ __align__(16) unsigned short BS[144 * 32];      //  9KB

  floatx4 acc[4][4];
#pragma unroll
  for (int im = 0; im < 4; ++im)
#pragma unroll
    for (int in = 0; in < 4; ++in) acc[im][in] = (floatx4)0.0f;

  const int srow = lane >> 2;
  const int soff = (((lane & 3) ^ ((lane >> 3) & 3)) * 8);   // swizzled source chunk
  const int sa = (lq ^ ((lm >> 1) & 3)) * 8;                 // A read column
  const unsigned short* catb =
      catF + ((size_t)b * ROWS + PADR + m0 + dy * 64 - 1) * 256;
  const unsigned short* ag = Wfb + ((size_t)(g * 3) * 256 + o0) * 512;

  // per-wave T-source pointers for B slots s = wv, wv+4, and 8 (wv==0 only);
  // scalar registers (no runtime-indexed array). OOB rows -> zpad.
  auto mk_tsrc = [&](int s) -> const unsigned short* {
    int p = m0 + dy * 64 - 1 + s * 16 + srow;
    bool v = ((unsigned)p < (unsigned)HWn);
    int aj = argb[(size_t)b * HWn + (v ? p : 0)];
    return v ? (vbf + ((size_t)b * HWn + aj) * 256) : zpad;
  };
  const unsigned short* tP0 = mk_tsrc(wv);
  const unsigned short* tP1 = mk_tsrc(wv + 4);
  const unsigned short* tP2 = (wv == 0) ? mk_tsrc(8) : zpad;
  const int s0 = wv, s1 = wv + 4;

  auto STAGE = [&](int kc) {
    // A: 6 groups per wave (flat slots l = wv + 4i, i=0..5, l<24)
#pragma unroll
    for (int i = 0; i < 6; ++i) {
      int l = wv + i * 4;
      int t = l >> 3, s = l & 7;
      gl_lds16(ag + ((size_t)(t * 256 + s * 16 + srow)) * 512 + kc + soff,
               &AS[(t * 128 + s * 16) * 32]);
    }
    // B: slots s0=wv, s1=wv+4, plus s=8 on wave 0
    if (kc < 256) {
      gl_lds16(catb + ((size_t)(s0 * 16 + srow)) * 256 + kc + soff,
               &BS[(s0 * 16) * 32]);
      gl_lds16(catb + ((size_t)(s1 * 16 + srow)) * 256 + kc + soff,
               &BS[(s1 * 16) * 32]);
      if (wv == 0)
        gl_lds16(catb + ((size_t)(8 * 16 + srow)) * 256 + kc + soff,
                 &BS[(8 * 16) * 32]);
    } else {
      int kk = kc - 256;
      gl_lds16(tP0 + kk + soff, &BS[(s0 * 16) * 32]);
      gl_lds16(tP1 + kk + soff, &BS[(s1 * 16) * 32]);
      if (wv == 0)
        gl_lds16(tP2 + kk + soff, &BS[(8 * 16) * 32]);
    }
  };
  auto COMPUTE = [&]() {
#pragma unroll
    for (int t = 0; t < 3; ++t) {   // t = dx+1
      bf16x8 afr[4];
#pragma unroll
      for (int im = 0; im < 4; ++im)
        afr[im] = *reinterpret_cast<const bf16x8*>(
            &AS[(t * 128 + wm * 64 + im * 16 + lm) * 32 + sa]);
#pragma unroll
      for (int in = 0; in < 4; ++in) {
        int u = wn * 64 + in * 16 + lm + t;   // p + 1 + dx
        int sb = (lq ^ ((u >> 1) & 3)) * 8;
        u16x8 braw = *reinterpret_cast<const u16x8*>(&BS[u * 32 + sb]);
        if ((t == 0 && in == 0 && lane_first) ||
            (t == 2 && in == 3 && lane_last))
          braw = (u16x8)(unsigned short)0;
        union { u16x8 u8; bf16x8 h; } cvt; cvt.u8 = braw;
#pragma unroll
        for (int im = 0; im < 4; ++im)
          acc[im][in] = __builtin_amdgcn_mfma_f32_16x16x32_bf16(
              afr[im], cvt.h, acc[im][in], 0, 0, 0);
      }
    }
  };

  for (int kci = 0; kci < 16; ++kci) {
    if (kci) __syncthreads();      // prior compute's LDS reads retired
    STAGE(kci * 32);
    __syncthreads();               // stage landed (vmcnt drained by barrier)
    COMPUTE();
  }

  unsigned short* P = Pg + ((size_t)(g * Bn + b) * Cn) * HWn;
#pragma unroll
  for (int in = 0; in < 4; ++in) {
    int p = m0 + wn * 64 + in * 16 + lm;
#pragma unroll
    for (int im = 0; im < 4; ++im) {
      int ob = o0 + wm * 64 + im * 16 + lq * 4;
#pragma unroll
      for (int r = 0; r < 4; ++r)
        P[(size_t)(ob + r) * HWn + p] = f2bf(acc[im][in][r]);
    }
  }
}

// ---------------------------------------------------------------------------
// L5: combine: out = fx + (P0+P1+P2 + bf)*S over bf16 partials, 8 elem/thread.
// ---------------------------------------------------------------------------
__global__ __launch_bounds__(256) void combine(
    const unsigned short* __restrict__ Pg, const float* __restrict__ fx,
    const float* __restrict__ bf, const float* __restrict__ star,
    float* __restrict__ out) {
  size_t e = ((size_t)blockIdx.x * 256 + threadIdx.x) * 8;
  int p = (int)(e & 4095);
  int bo = (int)(e >> 12);
  int o = bo & 255, b = bo >> 8;
  const size_t gs = (size_t)Bn * Cn * HWn;
  u16x8 q0 = *reinterpret_cast<const u16x8*>(Pg + e);
  u16x8 q1 = *reinterpret_cast<const u16x8*>(Pg + gs + e);
  u16x8 q2 = *reinterpret_cast<const u16x8*>(Pg + 2 * gs + e);
  float bias = bf[o];
  const float* sp = star + (size_t)b * HWn + p;
  const float* fp = fx + e;
  float* op = out + e;
#pragma unroll
  for (int h = 0; h < 2; ++h) {
    floatx4 s = *reinterpret_cast<const floatx4*>(sp + h * 4);
    floatx4 f = *reinterpret_cast<const floatx4*>(fp + h * 4);
    floatx4 r;
#pragma unroll
    for (int i = 0; i < 4; ++i) {
      int k = h * 4 + i;
      float a = bf2f(q0[k]) + bf2f(q1[k]) + bf2f(q2[k]);
      r[i] = f[i] + (a + bias) * s[i];
    }
    *reinterpret_cast<floatx4*>(op + h * 4) = r;
  }
}

// ---------------------------------------------------------------------------
extern "C" void kernel_launch(void* const* d_in, const int* in_sizes, int n_in,
                              void* d_out, int out_size, void* d_ws, size_t ws_size,
                              hipStream_t stream) {
  const float* front_x   = (const float*)d_in[0];
  const float* cross_x   = (const float*)d_in[1];
  const float* front_hat = (const float*)d_in[2];
  const float* Wq = (const float*)d_in[3];
  const float* bq = (const float*)d_in[4];
  const float* Wk = (const float*)d_in[5];
  const float* bk = (const float*)d_in[6];
  const float* Wv = (const float*)d_in[7];
  const float* bv = (const float*)d_in[8];
  const float* Wf = (const float*)d_in[9];
  const float* bf = (const float*)d_in[10];
  float* out = (float*)d_out;

  char* ws = (char*)d_ws;
  size_t off = 0;
  auto alloc = [&](size_t bytes) -> void* {
    void* p = (void*)(ws + off);
    off += (bytes + 255) & ~(size_t)255;
    return p;
  };
  unsigned short* Wvb = (unsigned short*)alloc(65536 * sizeof(unsigned short));
  unsigned short* Wfb = (unsigned short*)alloc((size_t)9 * 256 * 512 * sizeof(unsigned short));
  float* qf  = (float*)alloc((size_t)Bn * HWn * C8 * sizeof(float));
  float* kf  = (float*)alloc((size_t)Bn * HWn * C8 * sizeof(float));
  unsigned short* qhi = (unsigned short*)alloc((size_t)Bn * HWn * C8 * 2);
  unsigned short* qlo = (unsigned short*)alloc((size_t)Bn * HWn * C8 * 2);
  unsigned short* khi = (unsigned short*)alloc((size_t)Bn * HWn * C8 * 2);
  unsigned short* klo = (unsigned short*)alloc((size_t)Bn * HWn * C8 * 2);
  float*  star = (float*)alloc((size_t)Bn * HWn * sizeof(float));
  int*    argb = (int*)alloc((size_t)Bn * HWn * sizeof(int));
  int*    cnt  = (int*)alloc(256);
  int*    list = (int*)alloc((size_t)Bn * HWn * sizeof(int));
  unsigned short* xht = (unsigned short*)alloc((size_t)Bn * HWn * 256 * 2);
  unsigned short* vbf = (unsigned short*)alloc((size_t)Bn * HWn * 256 * 2);
  unsigned short* catF = (unsigned short*)alloc((size_t)Bn * ROWS * 256 * sizeof(unsigned short));
  unsigned short* zpad = (unsigned short*)alloc(256 * sizeof(unsigned short));
  unsigned short* Pg = (unsigned short*)alloc((size_t)3 * Bn * Cn * HWn * 2);  // 25 MB bf16

  // L1: proj [0,512) -> cat [512,1024) -> prep [1024,1184), sequential order
  proj_cat_prep<<<dim3(1184), dim3(1024), 0, stream>>>(
      cross_x, front_x, front_hat, Wq, bq, Wk, bk, Wv, Wf,
      qf, kf, qhi, qlo, khi, klo, Wvb, Wfb, catF, xht, zpad, cnt);

  // L2: energy, 64-query tile, distance-1 register prefetch
  energy_approx<<<dim3(HWn / 64, Bn), dim3(1024), 0, stream>>>(
      khi, klo, qhi, qlo, star, argb, cnt, list);

  // L3: projv [0,256) -> recheck [256,512), sequential order
  recheck_projv<<<dim3(512), dim3(256), 0, stream>>>(
      xht, Wvb, bv, vbf, qf, kf, cnt, list, star, argb);

  // L4: conv, single-buffer serial staging, 4 blocks/CU (zero tail)
  conv_mfma<<<dim3(HWn / 128, Cn / 128, Bn * 3), dim3(256), 0, stream>>>(
      catF, Wfb, vbf, argb, zpad, Pg);

  // L5: combine
  combine<<<dim3((Bn * Cn * HWn / 8) / 256), dim3(256), 0, stream>>>(
      Pg, front_x, bf, star, out);
}

// Round 17
// 212.661 us; speedup vs baseline: 1.0564x; 1.0564x over previous
//
#include <hip/hip_runtime.h>

#define Bn 4
#define Cn 256
#define C8 32
#define Hn 64
#define Wn 64
#define HWn 4096
#define PADR 80
#define ROWS (HWn + 2 * PADR)   // 4256 padded pixel-rows per batch
#define MARGIN 6e-3f

typedef __bf16 bf16x8 __attribute__((ext_vector_type(8)));
typedef float floatx4 __attribute__((ext_vector_type(4)));
typedef unsigned short u16x8 __attribute__((ext_vector_type(8)));

__device__ __forceinline__ unsigned short f2bf(float f) {
  union { float f; unsigned int u; } c; c.f = f;
  unsigned int u = c.u;
  return (unsigned short)((u + 0x7FFFu + ((u >> 16) & 1u)) >> 16);  // RNE
}
__device__ __forceinline__ float bf2f(unsigned short h) {
  union { unsigned int u; float f; } c; c.u = ((unsigned int)h) << 16;
  return c.f;
}
__device__ __forceinline__ void gl_lds16(const void* g, void* l) {
  __builtin_amdgcn_global_load_lds(
      (__attribute__((address_space(1))) void*)(uintptr_t)g,
      (__attribute__((address_space(3))) void*)(uintptr_t)l, 16, 0, 0);
}

// ---------------------------------------------------------------------------
// L1 (R20): proj / cat / prep co-launched, SEQUENTIAL block ordering:
// bx<512 proj, 512<=bx<1024 cat, bx>=1024 prep. Prep: tap-fused Wfb
// transpose (9 consecutive floats in, 9 coalesced bf16 streams out).
// ---------------------------------------------------------------------------
__global__ __launch_bounds__(1024) void proj_cat_prep(
    const float* __restrict__ cross_x, const float* __restrict__ front_x,
    const float* __restrict__ front_hat,
    const float* __restrict__ Wq, const float* __restrict__ bq,
    const float* __restrict__ Wk, const float* __restrict__ bk,
    const float* __restrict__ Wv, const float* __restrict__ Wf,
    float* __restrict__ qf, float* __restrict__ kf,
    unsigned short* __restrict__ qhi, unsigned short* __restrict__ qlo,
    unsigned short* __restrict__ khi, unsigned short* __restrict__ klo,
    unsigned short* __restrict__ Wvb, unsigned short* __restrict__ Wfb,
    unsigned short* __restrict__ catF, unsigned short* __restrict__ xht,
    unsigned short* __restrict__ zpad, int* __restrict__ cnt) {
  union SMu {
    struct { float Wl[8192]; float part[3 * 4 * 8 * 64]; } pj;   // 56KB
    unsigned short tile[4][64][66];                               // 33.8KB
  };
  __shared__ __align__(16) SMu sm;

  int bx = blockIdx.x;
  int tid1k = threadIdx.x;

  if (bx >= 1024) {
    // ================= prep path: 160 blocks x 1024 threads ================
    size_t t = (size_t)(bx - 1024) * 1024 + tid1k;
    if (t == 0) cnt[0] = 0;
    if (t < 256) zpad[t] = 0;
    if (t < 131072) {
      const float* src = Wf + t * 9;
#pragma unroll
      for (int k = 0; k < 9; ++k)
        Wfb[(size_t)k * 131072 + t] = f2bf(src[k]);
    }
    if (t < 163840) {           // catF pad rows (2*PADR rows x 256 ch x 4 b)
      int col = (int)(t & 255);
      int r4 = (int)(t >> 8);
      int bb = r4 / 160, rr = r4 % 160;
      int row = (rr < PADR) ? rr : (HWn + rr);
      catF[((size_t)bb * ROWS + row) * 256 + col] = 0;
    }
    if (t < 65536) Wvb[t] = f2bf(Wv[t]);   // [o][c] row-major already
    return;
  }

  if (bx >= 512) {
    // ================= cat path: id 0..511 =================
    int id = bx - 512;
    int j0 = (id & 63) * 64;
    int bz = id >> 6;                  // 0..7
    int b = bz >> 1, which = bz & 1;
    int g4 = tid1k >> 8;               // 4 groups of 256 threads
    int tid = tid1k & 255;
    int ci0 = g4 * 64;

    const float* src = (which == 0) ? front_x : front_hat;
#pragma unroll
    for (int u = tid; u < 1024; u += 256) {
      int cl = u >> 4, h4 = (u & 15) * 4;
      floatx4 v = *reinterpret_cast<const floatx4*>(
          &src[((size_t)(b * Cn + ci0 + cl)) * HWn + j0 + h4]);
#pragma unroll
      for (int k = 0; k < 4; ++k) sm.tile[g4][cl][h4 + k] = f2bf(v[k]);
    }
    __syncthreads();
#pragma unroll
    for (int u = tid; u < 512; u += 256) {
      int oct = u & 7, hw_l = u >> 3;
      u16x8 val;
#pragma unroll
      for (int k = 0; k < 8; ++k) val[k] = sm.tile[g4][oct * 8 + k][hw_l];
      if (which == 0)
        *reinterpret_cast<u16x8*>(
            &catF[((size_t)b * ROWS + PADR + j0 + hw_l) * 256 + ci0 + oct * 8]) = val;
      else
        *reinterpret_cast<u16x8*>(
            &xht[((size_t)b * HWn + j0 + hw_l) * 256 + ci0 + oct * 8]) = val;
    }
    return;
  }

  // ================= proj path: id 0..511 =================
  int id = bx;
  int tid = tid1k;
  int lane = tid & 63, wv = tid >> 6;    // 16 waves
  int slice = wv & 3;                    // o-slice (8 o each)
  int chunk = wv >> 2;                   // c-chunk (64 c each)
  int jb = id & 63;
  int b = (id >> 6) & 3;
  int z = id >> 8;
  int j = jb * 64 + lane;
  const float* x = (z == 0) ? cross_x : front_x;
  const float* Wraw = (z == 0) ? Wq : Wk;
  const float* bd = (z == 0) ? bq : bk;
  float* outp = (z == 0) ? qf : kf;
  unsigned short* hip_ = (z == 0) ? qhi : khi;
  unsigned short* lop_ = (z == 0) ? qlo : klo;
  int o0 = slice * 8;
  int c0 = chunk * 64;

  float* Wl = sm.pj.Wl;
  float* part = sm.pj.part;

  for (int u = tid; u < 8192; u += 1024) {
    int c = u >> 5, o = u & 31;
    Wl[u] = Wraw[o * 256 + c];                    // transpose on load (L2-hot)
  }
  __syncthreads();

  const float* xb = x + (size_t)b * Cn * HWn + j;
  floatx4 a0 = (floatx4)0.0f, a1 = (floatx4)0.0f;
#pragma unroll 16
  for (int c = c0; c < c0 + 64; ++c) {
    float xv = xb[(size_t)c * HWn];
    floatx4 wa = *reinterpret_cast<const floatx4*>(&Wl[c * 32 + o0]);      // broadcast
    floatx4 wb = *reinterpret_cast<const floatx4*>(&Wl[c * 32 + o0 + 4]);
    a0 += wa * xv;
    a1 += wb * xv;
  }
  if (chunk > 0) {
    float* dst = &part[(((chunk - 1) * 4 + slice) * 8) * 64];
#pragma unroll
    for (int o = 0; o < 4; ++o) { dst[o * 64 + lane] = a0[o]; dst[(o + 4) * 64 + lane] = a1[o]; }
  }
  __syncthreads();
  if (chunk != 0) return;
#pragma unroll
  for (int q = 0; q < 3; ++q) {
    const float* src = &part[((q * 4 + slice) * 8) * 64];
#pragma unroll
    for (int o = 0; o < 4; ++o) { a0[o] += src[o * 64 + lane]; a1[o] += src[(o + 4) * 64 + lane]; }
  }
  float acc[8];
#pragma unroll
  for (int o = 0; o < 4; ++o) { acc[o] = a0[o] + bd[o0 + o]; acc[o + 4] = a1[o] + bd[o0 + 4 + o]; }

  float* op = outp + ((size_t)b * HWn + j) * C8 + o0;
  u16x8 hv, lv;
#pragma unroll
  for (int o = 0; o < 8; ++o) {
    op[o] = acc[o];
    unsigned short h = f2bf(acc[o]);
    hv[o] = h;
    lv[o] = f2bf(acc[o] - bf2f(h));
  }
  *reinterpret_cast<u16x8*>(hip_ + ((size_t)b * HWn + j) * C8 + o0) = hv;
  *reinterpret_cast<u16x8*>(lop_ + ((size_t)b * HWn + j) * C8 + o0) = lv;
}

// ---------------------------------------------------------------------------
// L2 (R24 = R23): energy, 64-query tile + branchless med3 inner loop.
// (R25 post-mortem: manual distance-1 prefetch REGRESSED — compiler already
// pipelines these global loads; hand-pipelining added VGPR pressure and
// copies. Energy is pinned by its own schedule: traffic-halving null,
// occupancy null, manual prefetch negative.)
// ---------------------------------------------------------------------------
__global__ __launch_bounds__(1024) void energy_approx(
    const unsigned short* __restrict__ khi, const unsigned short* __restrict__ klo,
    const unsigned short* __restrict__ qhi, const unsigned short* __restrict__ qlo,
    float* __restrict__ star, int* __restrict__ argb,
    int* __restrict__ cnt, int* __restrict__ list) {
  int b = blockIdx.y;
  int j0 = blockIdx.x * 64;
  int tid = threadIdx.x;
  int lane = tid & 63, wv = tid >> 6;   // wv 0..15
  int lm = lane & 15, lq = lane >> 4;

  __shared__ float bv1S[16][64];
  __shared__ int   bi1S[16][64];
  __shared__ float bv2S[16][64];

  bf16x8 qh[4], ql[4];
#pragma unroll
  for (int s = 0; s < 4; ++s) {
    int j = j0 + s * 16 + lm;
    qh[s] = *reinterpret_cast<const bf16x8*>(qhi + ((size_t)b * HWn + j) * 32 + lq * 8);
    ql[s] = *reinterpret_cast<const bf16x8*>(qlo + ((size_t)b * HWn + j) * 32 + lq * 8);
  }
  const unsigned short* kh_base = khi + (size_t)b * HWn * 32 + lq * 8;
  const unsigned short* kl_base = klo + (size_t)b * HWn * 32 + lq * 8;

  float b1[4], b2[4];
#pragma unroll
  for (int s = 0; s < 4; ++s) { b1[s] = -3.0e38f; b2[s] = -3.0e38f; }

  int ibase = wv * 256;
#pragma unroll 4
  for (int it = 0; it < 16; ++it) {
    int i0 = ibase + it * 16;
    bf16x8 ah = *reinterpret_cast<const bf16x8*>(kh_base + (size_t)(i0 + lm) * 32);
    bf16x8 al = *reinterpret_cast<const bf16x8*>(kl_base + (size_t)(i0 + lm) * 32);
#pragma unroll
    for (int s = 0; s < 4; ++s) {
      floatx4 acc = (floatx4)0.0f;
      acc = __builtin_amdgcn_mfma_f32_16x16x32_bf16(ah, qh[s], acc, 0, 0, 0);
      acc = __builtin_amdgcn_mfma_f32_16x16x32_bf16(ah, ql[s], acc, 0, 0, 0);
      acc = __builtin_amdgcn_mfma_f32_16x16x32_bf16(al, qh[s], acc, 0, 0, 0);
#pragma unroll
      for (int r = 0; r < 4; ++r) {
        unsigned code = (unsigned)(it * 4 + r);   // SGPR-uniform per (it,r)
        union { float f; unsigned u; } cv; cv.f = acc[r];
        cv.u = (cv.u & ~63u) | code;              // v_and_or_b32
        float vp = cv.f;
        // exact new second-best: median(vp, b1_old, b2_old)
        b2[s] = __builtin_amdgcn_fmed3f(vp, b1[s], b2[s]);
        b1[s] = fmaxf(b1[s], vp);
      }
    }
  }
  int i1[4];
#pragma unroll
  for (int s = 0; s < 4; ++s) {
    union { float f; unsigned u; } cv; cv.f = b1[s];
    unsigned code = cv.u & 63u;                   // (it<<2)|r of the winner
    i1[s] = ibase + (int)(code >> 2) * 16 + lq * 4 + (int)(code & 3u);
  }
#pragma unroll
  for (int s = 0; s < 4; ++s) {
#pragma unroll
    for (int m = 16; m <= 32; m <<= 1) {
      float ob1 = __shfl_xor(b1[s], m, 64);
      int oi1 = __shfl_xor(i1[s], m, 64);
      float ob2 = __shfl_xor(b2[s], m, 64);
      float c2;
      if (ob1 > b1[s] || (ob1 == b1[s] && oi1 < i1[s])) {
        c2 = fmaxf(b1[s], ob2);
        b1[s] = ob1; i1[s] = oi1;
      } else {
        c2 = fmaxf(ob1, b2[s]);
      }
      b2[s] = c2;
    }
    if (lq == 0) {
      bv1S[wv][s * 16 + lm] = b1[s];
      bi1S[wv][s * 16 + lm] = i1[s];
      bv2S[wv][s * 16 + lm] = b2[s];
    }
  }
  __syncthreads();
  if (tid < 64) {
    float B1 = bv1S[0][tid];
    int I1 = bi1S[0][tid];
    float B2 = bv2S[0][tid];
#pragma unroll
    for (int w = 1; w < 16; ++w) {
      float v1 = bv1S[w][tid];
      int ii = bi1S[w][tid];
      float v2 = bv2S[w][tid];
      if (v1 > B1) { B2 = fmaxf(B1, v2); B1 = v1; I1 = ii; }
      else B2 = fmaxf(B2, v1);
    }
    size_t o = (size_t)b * HWn + j0 + tid;
    union { float f; unsigned u; } cs; cs.f = B1;
    cs.u &= ~63u;                                 // strip packed index bits
    star[o] = cs.f;
    argb[o] = I1;
    if (B1 - B2 < MARGIN) {
      int slot = atomicAdd(cnt, 1);
      list[slot] = (b << 12) | (j0 + (int)tid);
    }
  }
}

// ---------------------------------------------------------------------------
// L3 (R24 = R17): recheck CO-LAUNCHED with proj_v_mfma, even/odd interleave.
// ---------------------------------------------------------------------------
__global__ __launch_bounds__(256) void recheck_projv(
    const unsigned short* __restrict__ xht, const unsigned short* __restrict__ Wvb,
    const float* __restrict__ bv, unsigned short* __restrict__ vbf,
    const float* __restrict__ qf, const float* __restrict__ kf,
    const int* __restrict__ cnt, const int* __restrict__ list,
    float* __restrict__ star, int* __restrict__ argb) {
  int bx = blockIdx.x;
  if ((bx & 1) == 0) {
    // ================= proj_v path: id 0..255 =================
    int id = bx >> 1;
    int m0 = (id & 31) * 128;
    int o0 = ((id >> 5) & 1) * 128;
    int b = id >> 6;
    int tid = threadIdx.x;
    int lane = tid & 63, wv = tid >> 6;
    int wm = wv >> 1, wn = wv & 1;
    int lm = lane & 15, lq = lane >> 4;

    union SMu {
      struct { unsigned short A[2][128 * 32]; unsigned short B[2][128 * 32]; } st;
      unsigned short TS[128 * 136];
    };
    __shared__ __align__(16) SMu sm;

    floatx4 acc[4][4];
#pragma unroll
    for (int im = 0; im < 4; ++im)
#pragma unroll
      for (int in = 0; in < 4; ++in) acc[im][in] = (floatx4)0.0f;

    const int srow = lane >> 2;
    const int soff = (((lane & 3) ^ ((lane >> 3) & 3)) * 8);   // swizzled source chunk
    const int sa = (lq ^ ((lm >> 1) & 3)) * 8;                 // swizzled read column
    const unsigned short* ag = Wvb + (size_t)o0 * 256;
    const unsigned short* bg = xht + ((size_t)b * HWn + m0) * 256;

    auto STAGE = [&](int buf, int kc) {
#pragma unroll
      for (int i = 0; i < 2; ++i) {
        int r0 = wv * 32 + i * 16;
        gl_lds16(ag + ((size_t)(r0 + srow)) * 256 + kc + soff, &sm.st.A[buf][r0 * 32]);
        gl_lds16(bg + ((size_t)(r0 + srow)) * 256 + kc + soff, &sm.st.B[buf][r0 * 32]);
      }
    };
    auto COMPUTE = [&](int buf) {
      bf16x8 afr[4];
#pragma unroll
      for (int im = 0; im < 4; ++im)
        afr[im] = *reinterpret_cast<const bf16x8*>(
            &sm.st.A[buf][(wm * 64 + im * 16 + lm) * 32 + sa]);
#pragma unroll
      for (int in = 0; in < 4; ++in) {
        bf16x8 bfr = *reinterpret_cast<const bf16x8*>(
            &sm.st.B[buf][(wn * 64 + in * 16 + lm) * 32 + sa]);
#pragma unroll
        for (int im = 0; im < 4; ++im)
          acc[im][in] = __builtin_amdgcn_mfma_f32_16x16x32_bf16(
              afr[im], bfr, acc[im][in], 0, 0, 0);
      }
    };

    STAGE(0, 0);
#pragma unroll 2
    for (int st = 0; st < 8; ++st) {
      __builtin_amdgcn_s_barrier();            // buf[(st+1)&1] free to overwrite
      if (st < 7) {
        STAGE((st + 1) & 1, (st + 1) * 32);
        asm volatile("s_waitcnt vmcnt(4)" ::: "memory");   // tile st landed
      } else {
        asm volatile("s_waitcnt vmcnt(0)" ::: "memory");
      }
      __builtin_amdgcn_s_barrier();
      __builtin_amdgcn_sched_barrier(0);
      COMPUTE(st & 1);
    }
    __builtin_amdgcn_s_barrier();   // all waves done reading before TS overwrite

    // epilogue: TS aliases the (now dead) stage buffers.
#pragma unroll
    for (int in = 0; in < 4; ++in) {
      int pl = wn * 64 + in * 16 + lm;
#pragma unroll
      for (int im = 0; im < 4; ++im) {
#pragma unroll
        for (int r = 0; r < 4; ++r) {
          int ol = wm * 64 + im * 16 + lq * 4 + r;
          sm.TS[pl * 136 + ol] = f2bf(acc[im][in][r] + bv[o0 + ol]);
        }
      }
    }
    __syncthreads();
    for (int idx = tid; idx < 128 * 16; idx += 256) {
      int p = idx >> 4, ch = idx & 15;
      u16x8 val = *reinterpret_cast<const u16x8*>(&sm.TS[p * 136 + ch * 8]);
      *reinterpret_cast<u16x8*>(
          &vbf[((size_t)b * HWn + m0 + p) * 256 + o0 + ch * 8]) = val;
    }
  } else {
    // ================= recheck path: stride 256 over list =================
    __shared__ double bvS[4];
    __shared__ int biS[4];
    int n = cnt[0];
    int tid = threadIdx.x;
    int lane = tid & 63, wv = tid >> 6;
    for (int idx = bx >> 1; idx < n; idx += 256) {
      int e = list[idx];
      int b = e >> 12, j = e & 4095;
      const float* qp = qf + ((size_t)b * HWn + j) * 32;
      double qj[32];
#pragma unroll
      for (int o = 0; o < 32; ++o) qj[o] = (double)qp[o];
      double best = -1.0e300;
      int bi = 1 << 30;
      for (int i = tid; i < HWn; i += 256) {
        const float* kp = kf + ((size_t)b * HWn + i) * 32;
        double s = 0.0;
#pragma unroll
        for (int o = 0; o < 32; ++o) s += (double)kp[o] * qj[o];
        if (s > best) { best = s; bi = i; }
      }
#pragma unroll
      for (int m = 1; m < 64; m <<= 1) {
        double ob = __shfl_xor(best, m, 64);
        int oi = __shfl_xor(bi, m, 64);
        if (ob > best || (ob == best && oi < bi)) { best = ob; bi = oi; }
      }
      if (lane == 0) { bvS[wv] = best; biS[wv] = bi; }
      __syncthreads();
      if (tid == 0) {
#pragma unroll
        for (int w = 1; w < 4; ++w) {
          if (bvS[w] > best || (bvS[w] == best && biS[w] < bi)) {
            best = bvS[w]; bi = biS[w];
          }
        }
        star[(size_t)b * HWn + j] = (float)best;
        argb[(size_t)b * HWn + j] = bi;
      }
      __syncthreads();
    }
  }
}

// ---------------------------------------------------------------------------
// L4 (R24): conv3x3 implicit GEMM, single-buffer serial staging + flat
// T-gather, 4 blocks/CU (zero tail). Proven ~45 us.
// ---------------------------------------------------------------------------
__global__ __launch_bounds__(256) void conv_mfma(
    const unsigned short* __restrict__ catF, const unsigned short* __restrict__ Wfb,
    const unsigned short* __restrict__ vbf, const int* __restrict__ argb,
    const unsigned short* __restrict__ zpad, unsigned short* __restrict__ Pg) {
  int m0 = blockIdx.x * 128;
  int o0 = blockIdx.y * 128;
  int bz = blockIdx.z;
  int b = bz / 3, g = bz % 3;      // g = dy+1
  int dy = g - 1;
  int tid = threadIdx.x;
  int lane = tid & 63;
  int wv = tid >> 6;
  int wm = wv >> 1, wn = wv & 1;
  int lm = lane & 15, lq = lane >> 4;
  const bool lane_first = (lm == 0);
  const bool lane_last = (lm == 15);

  __shared__ __align__(16) unsigned short AS[3 * 128 * 32];  // 24KB
  __shared__ __align__(16) unsigned short BS[144 * 32];      //  9KB

  floatx4 acc[4][4];
#pragma unroll
  for (int im = 0; im < 4; ++im)
#pragma unroll
    for (int in = 0; in < 4; ++in) acc[im][in] = (floatx4)0.0f;

  const int srow = lane >> 2;
  const int soff = (((lane & 3) ^ ((lane >> 3) & 3)) * 8);   // swizzled source chunk
  const int sa = (lq ^ ((lm >> 1) & 3)) * 8;                 // A read column
  const unsigned short* catb =
      catF + ((size_t)b * ROWS + PADR + m0 + dy * 64 - 1) * 256;
  const unsigned short* ag = Wfb + ((size_t)(g * 3) * 256 + o0) * 512;

  // per-wave T-source pointers for B slots s = wv, wv+4, and 8 (wv==0 only);
  // scalar registers (no runtime-indexed array). OOB rows -> zpad.
  auto mk_tsrc = [&](int s) -> const unsigned short* {
    int p = m0 + dy * 64 - 1 + s * 16 + srow;
    bool v = ((unsigned)p < (unsigned)HWn);
    int aj = argb[(size_t)b * HWn + (v ? p : 0)];
    return v ? (vbf + ((size_t)b * HWn + aj) * 256) : zpad;
  };
  const unsigned short* tP0 = mk_tsrc(wv);
  const unsigned short* tP1 = mk_tsrc(wv + 4);
  const unsigned short* tP2 = (wv == 0) ? mk_tsrc(8) : zpad;
  const int s0 = wv, s1 = wv + 4;

  auto STAGE = [&](int kc) {
    // A: 6 groups per wave (flat slots l = wv + 4i, i=0..5, l<24)
#pragma unroll
    for (int i = 0; i < 6; ++i) {
      int l = wv + i * 4;
      int t = l >> 3, s = l & 7;
      gl_lds16(ag + ((size_t)(t * 256 + s * 16 + srow)) * 512 + kc + soff,
               &AS[(t * 128 + s * 16) * 32]);
    }
    // B: slots s0=wv, s1=wv+4, plus s=8 on wave 0
    if (kc < 256) {
      gl_lds16(catb + ((size_t)(s0 * 16 + srow)) * 256 + kc + soff,
               &BS[(s0 * 16) * 32]);
      gl_lds16(catb + ((size_t)(s1 * 16 + srow)) * 256 + kc + soff,
               &BS[(s1 * 16) * 32]);
      if (wv == 0)
        gl_lds16(catb + ((size_t)(8 * 16 + srow)) * 256 + kc + soff,
                 &BS[(8 * 16) * 32]);
    } else {
      int kk = kc - 256;
      gl_lds16(tP0 + kk + soff, &BS[(s0 * 16) * 32]);
      gl_lds16(tP1 + kk + soff, &BS[(s1 * 16) * 32]);
      if (wv == 0)
        gl_lds16(tP2 + kk + soff, &BS[(8 * 16) * 32]);
    }
  };
  auto COMPUTE = [&]() {
#pragma unroll
    for (int t = 0; t < 3; ++t) {   // t = dx+1
      bf16x8 afr[4];
#pragma unroll
      for (int im = 0; im < 4; ++im)
        afr[im] = *reinterpret_cast<const bf16x8*>(
            &AS[(t * 128 + wm * 64 + im * 16 + lm) * 32 + sa]);
#pragma unroll
      for (int in = 0; in < 4; ++in) {
        int u = wn * 64 + in * 16 + lm + t;   // p + 1 + dx
        int sb = (lq ^ ((u >> 1) & 3)) * 8;
        u16x8 braw = *reinterpret_cast<const u16x8*>(&BS[u * 32 + sb]);
        if ((t == 0 && in == 0 && lane_first) ||
            (t == 2 && in == 3 && lane_last))
          braw = (u16x8)(unsigned short)0;
        union { u16x8 u8; bf16x8 h; } cvt; cvt.u8 = braw;
#pragma unroll
        for (int im = 0; im < 4; ++im)
          acc[im][in] = __builtin_amdgcn_mfma_f32_16x16x32_bf16(
              afr[im], cvt.h, acc[im][in], 0, 0, 0);
      }
    }
  };

  for (int kci = 0; kci < 16; ++kci) {
    if (kci) __syncthreads();      // prior compute's LDS reads retired
    STAGE(kci * 32);
    __syncthreads();               // stage landed (vmcnt drained by barrier)
    COMPUTE();
  }

  unsigned short* P = Pg + ((size_t)(g * Bn + b) * Cn) * HWn;
#pragma unroll
  for (int in = 0; in < 4; ++in) {
    int p = m0 + wn * 64 + in * 16 + lm;
#pragma unroll
    for (int im = 0; im < 4; ++im) {
      int ob = o0 + wm * 64 + im * 16 + lq * 4;
#pragma unroll
      for (int r = 0; r < 4; ++r)
        P[(size_t)(ob + r) * HWn + p] = f2bf(acc[im][in][r]);
    }
  }
}

// ---------------------------------------------------------------------------
// L5: combine: out = fx + (P0+P1+P2 + bf)*S over bf16 partials, 8 elem/thread.
// ---------------------------------------------------------------------------
__global__ __launch_bounds__(256) void combine(
    const unsigned short* __restrict__ Pg, const float* __restrict__ fx,
    const float* __restrict__ bf, const float* __restrict__ star,
    float* __restrict__ out) {
  size_t e = ((size_t)blockIdx.x * 256 + threadIdx.x) * 8;
  int p = (int)(e & 4095);
  int bo = (int)(e >> 12);
  int o = bo & 255, b = bo >> 8;
  const size_t gs = (size_t)Bn * Cn * HWn;
  u16x8 q0 = *reinterpret_cast<const u16x8*>(Pg + e);
  u16x8 q1 = *reinterpret_cast<const u16x8*>(Pg + gs + e);
  u16x8 q2 = *reinterpret_cast<const u16x8*>(Pg + 2 * gs + e);
  float bias = bf[o];
  const float* sp = star + (size_t)b * HWn + p;
  const float* fp = fx + e;
  float* op = out + e;
#pragma unroll
  for (int h = 0; h < 2; ++h) {
    floatx4 s = *reinterpret_cast<const floatx4*>(sp + h * 4);
    floatx4 f = *reinterpret_cast<const floatx4*>(fp + h * 4);
    floatx4 r;
#pragma unroll
    for (int i = 0; i < 4; ++i) {
      int k = h * 4 + i;
      float a = bf2f(q0[k]) + bf2f(q1[k]) + bf2f(q2[k]);
      r[i] = f[i] + (a + bias) * s[i];
    }
    *reinterpret_cast<floatx4*>(op + h * 4) = r;
  }
}

// ---------------------------------------------------------------------------
extern "C" void kernel_launch(void* const* d_in, const int* in_sizes, int n_in,
                              void* d_out, int out_size, void* d_ws, size_t ws_size,
                              hipStream_t stream) {
  const float* front_x   = (const float*)d_in[0];
  const float* cross_x   = (const float*)d_in[1];
  const float* front_hat = (const float*)d_in[2];
  const float* Wq = (const float*)d_in[3];
  const float* bq = (const float*)d_in[4];
  const float* Wk = (const float*)d_in[5];
  const float* bk = (const float*)d_in[6];
  const float* Wv = (const float*)d_in[7];
  const float* bv = (const float*)d_in[8];
  const float* Wf = (const float*)d_in[9];
  const float* bf = (const float*)d_in[10];
  float* out = (float*)d_out;

  char* ws = (char*)d_ws;
  size_t off = 0;
  auto alloc = [&](size_t bytes) -> void* {
    void* p = (void*)(ws + off);
    off += (bytes + 255) & ~(size_t)255;
    return p;
  };
  unsigned short* Wvb = (unsigned short*)alloc(65536 * sizeof(unsigned short));
  unsigned short* Wfb = (unsigned short*)alloc((size_t)9 * 256 * 512 * sizeof(unsigned short));
  float* qf  = (float*)alloc((size_t)Bn * HWn * C8 * sizeof(float));
  float* kf  = (float*)alloc((size_t)Bn * HWn * C8 * sizeof(float));
  unsigned short* qhi = (unsigned short*)alloc((size_t)Bn * HWn * C8 * 2);
  unsigned short* qlo = (unsigned short*)alloc((size_t)Bn * HWn * C8 * 2);
  unsigned short* khi = (unsigned short*)alloc((size_t)Bn * HWn * C8 * 2);
  unsigned short* klo = (unsigned short*)alloc((size_t)Bn * HWn * C8 * 2);
  float*  star = (float*)alloc((size_t)Bn * HWn * sizeof(float));
  int*    argb = (int*)alloc((size_t)Bn * HWn * sizeof(int));
  int*    cnt  = (int*)alloc(256);
  int*    list = (int*)alloc((size_t)Bn * HWn * sizeof(int));
  unsigned short* xht = (unsigned short*)alloc((size_t)Bn * HWn * 256 * 2);
  unsigned short* vbf = (unsigned short*)alloc((size_t)Bn * HWn * 256 * 2);
  unsigned short* catF = (unsigned short*)alloc((size_t)Bn * ROWS * 256 * sizeof(unsigned short));
  unsigned short* zpad = (unsigned short*)alloc(256 * sizeof(unsigned short));
  unsigned short* Pg = (unsigned short*)alloc((size_t)3 * Bn * Cn * HWn * 2);  // 25 MB bf16

  // L1: proj [0,512) -> cat [512,1024) -> prep [1024,1184), sequential order
  proj_cat_prep<<<dim3(1184), dim3(1024), 0, stream>>>(
      cross_x, front_x, front_hat, Wq, bq, Wk, bk, Wv, Wf,
      qf, kf, qhi, qlo, khi, klo, Wvb, Wfb, catF, xht, zpad, cnt);

  // L2: energy, 64-query tile
  energy_approx<<<dim3(HWn / 64, Bn), dim3(1024), 0, stream>>>(
      khi, klo, qhi, qlo, star, argb, cnt, list);

  // L3: recheck + v-projection co-launched (even/odd)
  recheck_projv<<<dim3(512), dim3(256), 0, stream>>>(
      xht, Wvb, bv, vbf, qf, kf, cnt, list, star, argb);

  // L4: conv, single-buffer serial staging, 4 blocks/CU (zero tail)
  conv_mfma<<<dim3(HWn / 128, Cn / 128, Bn * 3), dim3(256), 0, stream>>>(
      catF, Wfb, vbf, argb, zpad, Pg);

  // L5: combine
  combine<<<dim3((Bn * Cn * HWn / 8) / 256), dim3(256), 0, stream>>>(
      Pg, front_x, bf, star, out);
}